// Round 6
// baseline (783.581 us; speedup 1.0000x reference)
//
#include <hip/hip_runtime.h>
#include <hip/hip_cooperative_groups.h>
#include <stdint.h>

namespace cg = cooperative_groups;

#define D_IN 128
#define D_OUT 128
#define NREL 8
#define NBASE 4
#define NBLK 1024  // build kernel grid (co-resident: 4 blocks/CU of 256 thr)

typedef __attribute__((ext_vector_type(8))) short short8;
typedef __attribute__((ext_vector_type(4))) float floatx4;
typedef __attribute__((ext_vector_type(2))) float floatx2;

__device__ __forceinline__ unsigned short f2bf(float f) {
  unsigned int u = __float_as_uint(f);
  u += 0x7fffu + ((u >> 16) & 1u);
  return (unsigned short)(u >> 16);
}
__device__ __forceinline__ unsigned pack2bf(float lo, float hi) {
  return (unsigned)f2bf(lo) | ((unsigned)f2bf(hi) << 16);
}
__device__ __forceinline__ float bflo(unsigned int u) { return __uint_as_float(u << 16); }
__device__ __forceinline__ float bfhi(unsigned int u) { return __uint_as_float(u & 0xffff0000u); }

// ---------- 1) cooperative build: zero+cast+W2T | count | scan | bucket ----
// Replaces 5 dispatches (memset, prep, scan1, scan23, bucket) with one
// cooperative kernel; block-local scan values persist in regs across
// grid.sync(), eliminating the localsc round-trip.
// Record: (src, val|rel) — rel in low 3 mantissa bits of val (<=2^-20 rel err)
// so the agg kernel's per-edge live state is 2 regs, not 3.
__global__ __launch_bounds__(256)
void k_build(const float4* __restrict__ X, ushort4* __restrict__ Xb, int n4,
             const float* __restrict__ w_bases, unsigned short* __restrict__ W2T,
             const int* __restrict__ esrc, const int* __restrict__ edst,
             const int* __restrict__ erel, const float* __restrict__ eval_,
             int* __restrict__ counts, int* __restrict__ offsets,
             int* __restrict__ cursor, int* __restrict__ bsum,
             int* __restrict__ bpre, uint2* __restrict__ bucket, int Nn, int E) {
  cg::grid_group grid = cg::this_grid();
  const int tid = blockIdx.x * 256 + threadIdx.x;
  const int nth = NBLK * 256;
  __shared__ int s[256];

  // P0: zero counts + cast X fp32->bf16 + W2T[o][c]=w_bases[b][k][o], c=k*4+b
  const int ncu4 = (Nn + 3) >> 2;
  for (int i = tid; i < ncu4; i += nth) ((uint4*)counts)[i] = make_uint4(0u, 0u, 0u, 0u);
  for (int i = tid; i < n4; i += nth) {
    float4 v = X[i];
    ushort4 o;
    o.x = f2bf(v.x); o.y = f2bf(v.y); o.z = f2bf(v.z); o.w = f2bf(v.w);
    Xb[i] = o;
  }
  for (int i = tid; i < 128 * 512; i += nth) {
    int o = i >> 9, c = i & 511;
    int k = c >> 2, b = c & 3;
    W2T[i] = f2bf(w_bases[(b * D_IN + k) * D_OUT + o]);
  }
  grid.sync();

  // P1: count
  for (int i = tid; i < E; i += nth) atomicAdd(&counts[edst[i]], 1);
  grid.sync();

  // P2: block-local inclusive scan, one element/thread (NBLK*256 >= Nn)
  int v = (tid < Nn) ? counts[tid] : 0;
  s[threadIdx.x] = v;
  __syncthreads();
  for (int off = 1; off < 256; off <<= 1) {
    int t = 0;
    if (threadIdx.x >= off) t = s[threadIdx.x - off];
    __syncthreads();
    s[threadIdx.x] += t;
    __syncthreads();
  }
  const int locincl = s[threadIdx.x];
  if (threadIdx.x == 255) bsum[blockIdx.x] = locincl;
  grid.sync();

  // P3: block 0 exclusive-scans NBLK block sums (4 per thread)
  if (blockIdx.x == 0) {
    const int base = threadIdx.x * 4;
    int b0 = bsum[base], b1 = bsum[base + 1], b2 = bsum[base + 2], b3 = bsum[base + 3];
    int tsum = b0 + b1 + b2 + b3;
    s[threadIdx.x] = tsum;
    __syncthreads();
    for (int off = 1; off < 256; off <<= 1) {
      int t = 0;
      if (threadIdx.x >= off) t = s[threadIdx.x - off];
      __syncthreads();
      s[threadIdx.x] += t;
      __syncthreads();
    }
    int excl = s[threadIdx.x] - tsum;
    bpre[base] = excl;
    bpre[base + 1] = excl + b0;
    bpre[base + 2] = excl + b0 + b1;
    bpre[base + 3] = excl + b0 + b1 + b2;
  }
  grid.sync();

  // P4: offsets/cursor
  const int pre = bpre[blockIdx.x];
  if (tid < Nn) {
    int o = pre + locincl - v;
    offsets[tid] = o;
    cursor[tid] = o;
  }
  if (tid == 0) offsets[Nn] = E;
  grid.sync();

  // P5: bucket (8B record: src, val|rel)
  for (int i = tid; i < E; i += nth) {
    int d = edst[i];
    int pos = atomicAdd(&cursor[d], 1);
    unsigned vr = (__float_as_uint(eval_[i]) & ~7u) | (unsigned)erel[i];
    bucket[pos] = make_uint2((unsigned)esrc[i], vr);
  }
}

// ---------- 2) fused: per-dst basis aggregation (LDS) + MFMA transform ----------
// Block = 4 waves, 32 dst rows (33.8KB LDS -> 4 blocks/CU = 16 waves/CU).
// Wave w owns dsts [w*8, w*8+8) = ONE contiguous bucket range; records
// chunk-loaded cooperatively (64/load, double-buffered, __shfl distribute);
// depth-4 pipeline, 16 gathers in flight. Per-edge live state is 2 regs
// (vr, y) — src is consumed by the gather inside LOADG [R5 lesson: 3-reg
// state made the compiler sink gathers and collapse the pipeline at 52 VGPR].
__global__ __launch_bounds__(256, 4)
void k_agg_gemm(const uint2* __restrict__ bucket, const int* __restrict__ offsets,
                const float* __restrict__ w_rel_g, const unsigned* __restrict__ Xb2,
                const unsigned short* __restrict__ W2T, float* __restrict__ out, int Nn) {
  __shared__ __align__(16) unsigned short aggS[32][520];  // pitch 520: 2-way alias (free)
  __shared__ __align__(16) float wrS[NREL * NBASE];
  if (threadIdx.x < NREL * NBASE) wrS[threadIdx.x] = w_rel_g[threadIdx.x];
  __syncthreads();

  const int wave = threadIdx.x >> 6, lane = threadIdx.x & 63;
  const int d0 = blockIdx.x * 32 + wave * 8;
  const unsigned* __restrict__ Xl = Xb2 + lane;
  const floatx2 zf2 = {0.f, 0.f};

  // lane l (0..8) loads offsets[d0+l]; readlane -> SGPR bounds
  int oidx = d0 + (lane < 8 ? lane : 8);
  if (oidx > Nn) oidx = Nn;
  const int offv = offsets[oidx];
  const int s0 = __builtin_amdgcn_readlane(offv, 0);
  const int e8 = __builtin_amdgcn_readlane(offv, 8);

  floatx2 a0 = zf2, a1 = zf2, a2 = zf2, a3 = zf2;
  int row = 0;
  int bnd = __builtin_amdgcn_readlane(offv, 1);

#define FLUSH()                                                      \
  do {                                                               \
    uint4 o_;                                                        \
    o_.x = pack2bf(a0.x, a1.x);                                      \
    o_.y = pack2bf(a2.x, a3.x);                                      \
    o_.z = pack2bf(a0.y, a1.y);                                      \
    o_.w = pack2bf(a2.y, a3.y);                                      \
    *(uint4*)&aggS[wave * 8 + row][lane * 8] = o_;                   \
    a0 = zf2; a1 = zf2; a2 = zf2; a3 = zf2;                          \
    ++row;                                                           \
    bnd = (row < 8) ? __builtin_amdgcn_readlane(offv, row + 1)       \
                    : 0x7fffffff;                                    \
  } while (0)

  // ACCT: V = val|rel bits, Y = gathered 2xbf16
#define ACCT(EI, V, Y)                                               \
  do {                                                               \
    if ((EI) < e8) {                                                 \
      while ((EI) == bnd) FLUSH();                                   \
      const float4 w_ = *(const float4*)&wrS[((V) & 7u) * 4];        \
      const float val_ = __uint_as_float((V) & ~7u);                 \
      const float c0_ = val_ * w_.x, c1_ = val_ * w_.y;              \
      const float c2_ = val_ * w_.z, c3_ = val_ * w_.w;              \
      floatx2 x_;                                                    \
      x_.x = bflo(Y);                                                \
      x_.y = bfhi(Y);                                                \
      a0 += c0_ * x_;                                                \
      a1 += c1_ * x_;                                                \
      a2 += c2_ * x_;                                                \
      a3 += c3_ * x_;                                                \
    }                                                                \
  } while (0)

  // LOADG: rotate chunk if needed, shuffle 4 records, issue 4 gathers.
  // src shuffled to a temp and consumed by the gather immediately.
  // Invariant: group bases === s0 (mod 4), chunk bounds === s0 (mod 64).
#define LOADG(P, BASE)                                               \
  do {                                                               \
    int t0_ = (BASE); if (t0_ > ce) t0_ = ce;                        \
    if (t0_ - cbase >= 64) {                                         \
      cbase += 64;                                                   \
      chC = chN;                                                     \
      int in_ = cbase + 64 + lane;                                   \
      if (in_ > ce) in_ = ce;                                        \
      chN = bucket[in_];                                             \
    }                                                                \
    int t1_ = (BASE) + 1; if (t1_ > ce) t1_ = ce;                    \
    int t2_ = (BASE) + 2; if (t2_ > ce) t2_ = ce;                    \
    int t3_ = (BASE) + 3; if (t3_ > ce) t3_ = ce;                    \
    const int j0_ = t0_ - cbase, j1_ = t1_ - cbase;                  \
    const int j2_ = t2_ - cbase, j3_ = t3_ - cbase;                  \
    unsigned g0_ = __shfl(chC.x, j0_); v##P##0 = __shfl(chC.y, j0_); \
    unsigned g1_ = __shfl(chC.x, j1_); v##P##1 = __shfl(chC.y, j1_); \
    unsigned g2_ = __shfl(chC.x, j2_); v##P##2 = __shfl(chC.y, j2_); \
    unsigned g3_ = __shfl(chC.x, j3_); v##P##3 = __shfl(chC.y, j3_); \
    y##P##0 = Xl[g0_ << 6];                                          \
    y##P##1 = Xl[g1_ << 6];                                          \
    y##P##2 = Xl[g2_ << 6];                                          \
    y##P##3 = Xl[g3_ << 6];                                          \
  } while (0)

  if (s0 < e8) {
    const int ce = e8 - 1;
    // chunk double buffer: per-lane 8B record load covers 64 edges
    int cbase = s0;
    uint2 chC, chN;
    {
      int i0 = cbase + lane;
      if (i0 > ce) i0 = ce;
      chC = bucket[i0];
      int i1 = cbase + 64 + lane;
      if (i1 > ce) i1 = ce;
      chN = bucket[i1];
    }
    unsigned vA0, vA1, vA2, vA3, yA0, yA1, yA2, yA3;
    unsigned vB0, vB1, vB2, vB3, yB0, yB1, yB2, yB3;
    unsigned vC0, vC1, vC2, vC3, yC0, yC1, yC2, yC3;
    unsigned vD0, vD1, vD2, vD3, yD0, yD1, yD2, yD3;
    LOADG(A, s0);
    LOADG(B, s0 + 4);
    LOADG(C, s0 + 8);
    int gi = s0;
    while (gi < e8) {
      LOADG(D, gi + 12);
      ACCT(gi, vA0, yA0);
      ACCT(gi + 1, vA1, yA1);
      ACCT(gi + 2, vA2, yA2);
      ACCT(gi + 3, vA3, yA3);
      LOADG(A, gi + 16);
      ACCT(gi + 4, vB0, yB0);
      ACCT(gi + 5, vB1, yB1);
      ACCT(gi + 6, vB2, yB2);
      ACCT(gi + 7, vB3, yB3);
      LOADG(B, gi + 20);
      ACCT(gi + 8, vC0, yC0);
      ACCT(gi + 9, vC1, yC1);
      ACCT(gi + 10, vC2, yC2);
      ACCT(gi + 11, vC3, yC3);
      LOADG(C, gi + 24);
      ACCT(gi + 12, vD0, yD0);
      ACCT(gi + 13, vD1, yD1);
      ACCT(gi + 14, vD2, yD2);
      ACCT(gi + 15, vD3, yD3);
      gi += 16;
    }
  }
  while (row < 8) FLUSH();  // trailing (and fully-empty) rows

  __syncthreads();

  // ---- phase 2: 32x128 output tile via 16x16x32 MFMA, K=512 ----
  const int q = lane >> 4, r16 = lane & 15;
  const int wn = wave * 32;
  const floatx4 zero = {0.f, 0.f, 0.f, 0.f};
  floatx4 acc[2][2];
  acc[0][0] = zero; acc[0][1] = zero; acc[1][0] = zero; acc[1][1] = zero;

#pragma unroll 4
  for (int k0 = 0; k0 < 512; k0 += 32) {
    int ka = k0 + q * 8;
    short8 af[2], bfv[2];
    af[0] = *(const short8*)&aggS[r16][ka];
    af[1] = *(const short8*)&aggS[16 + r16][ka];
    bfv[0] = *(const short8*)(W2T + (size_t)(wn + r16) * 512 + ka);
    bfv[1] = *(const short8*)(W2T + (size_t)(wn + 16 + r16) * 512 + ka);
#pragma unroll
    for (int i = 0; i < 2; ++i)
#pragma unroll
      for (int j = 0; j < 2; ++j)
        acc[i][j] = __builtin_amdgcn_mfma_f32_16x16x32_bf16(af[i], bfv[j], acc[i][j], 0, 0, 0);
  }

  // epilogue: C/D layout col=lane&15, row=(lane>>4)*4+p  [m89/m91-verified]
#pragma unroll
  for (int i = 0; i < 2; ++i) {
#pragma unroll
    for (int j = 0; j < 2; ++j) {
#pragma unroll
      for (int p = 0; p < 4; ++p) {
        int prow = i * 16 + q * 4 + p;
        int col = wn + j * 16 + r16;
        int grow = blockIdx.x * 32 + prow;
        if (grow < Nn) out[(size_t)grow * 128 + col] = acc[i][j][p];
      }
    }
  }
}

extern "C" void kernel_launch(void* const* d_in, const int* in_sizes, int n_in,
                              void* d_out, int out_size, void* d_ws, size_t ws_size,
                              hipStream_t stream) {
  const float* X = (const float*)d_in[0];
  const int* esrc = (const int*)d_in[1];
  const int* edst = (const int*)d_in[2];
  const int* erel = (const int*)d_in[3];
  const float* eval_ = (const float*)d_in[4];
  const float* w_bases = (const float*)d_in[5];
  const float* w_rel = (const float*)d_in[6];
  int Nn = in_sizes[0] / D_IN;  // 100000
  int E = in_sizes[1];          // 640000

  char* ws = (char*)d_ws;
  size_t off = 0;
  auto alloc = [&](size_t bytes) -> char* {
    char* p = ws + off;
    off += (bytes + 255) & ~(size_t)255;
    return p;
  };
  unsigned short* Xb = (unsigned short*)alloc((size_t)Nn * D_IN * 2);     // 25.6 MB
  unsigned short* W2T = (unsigned short*)alloc((size_t)128 * 512 * 2);    // 128 KB
  int* counts = (int*)alloc((size_t)(Nn + 4) * 4);
  int* cursor = (int*)alloc((size_t)Nn * 4);
  int* offsets = (int*)alloc((size_t)(Nn + 1) * 4);
  int* bsum = (int*)alloc((size_t)NBLK * 4);
  int* bpre = (int*)alloc((size_t)NBLK * 4);
  uint2* bucket = (uint2*)alloc((size_t)E * 8);                           // 5.1 MB
  (void)ws_size;

  int n4 = Nn * D_IN / 4;  // 3.2M

  // single cooperative build kernel (zero+cast+W2T, count, scan, bucket)
  const float4* X4 = (const float4*)X;
  ushort4* Xb4 = (ushort4*)Xb;
  void* args[] = {&X4, &Xb4, &n4, &w_bases, &W2T, &esrc, &edst, &erel, &eval_,
                  &counts, &offsets, &cursor, &bsum, &bpre, &bucket, &Nn, &E};
  hipLaunchCooperativeKernel(reinterpret_cast<void*>(k_build), dim3(NBLK), dim3(256),
                             args, 0, stream);

  // fused aggregation + transform: 4-wave blocks, 32 dsts each
  k_agg_gemm<<<(Nn + 31) / 32, 256, 0, stream>>>(bucket, offsets, w_rel,
                                                 (const unsigned*)Xb, W2T,
                                                 (float*)d_out, Nn);
}

// Round 8
// 249.949 us; speedup vs baseline: 3.1350x; 3.1350x over previous
//
#include <hip/hip_runtime.h>
#include <stdint.h>

#define D_IN 128
#define D_OUT 128
#define NREL 8
#define NBASE 4

typedef __attribute__((ext_vector_type(8))) short short8;
typedef __attribute__((ext_vector_type(4))) float floatx4;
typedef __attribute__((ext_vector_type(2))) float floatx2;

__device__ __forceinline__ unsigned short f2bf(float f) {
  unsigned int u = __float_as_uint(f);
  u += 0x7fffu + ((u >> 16) & 1u);
  return (unsigned short)(u >> 16);
}
__device__ __forceinline__ unsigned pack2bf(float lo, float hi) {
  return (unsigned)f2bf(lo) | ((unsigned)f2bf(hi) << 16);
}
__device__ __forceinline__ float bflo(unsigned int u) { return __uint_as_float(u << 16); }
__device__ __forceinline__ float bfhi(unsigned int u) { return __uint_as_float(u & 0xffff0000u); }

// ---------- 1) prep: cast X fp32->bf16 + build W2T + count (counts zeroed
// by hipMemsetAsync) ----------
// W2T[o][c] = w_bases[b][k][o], c = k*4+b  (bf16, [128][512])
__global__ void k_prep(const float4* __restrict__ X, ushort4* __restrict__ Xb, int n4,
                       const float* __restrict__ w_bases, unsigned short* __restrict__ W2T,
                       const int* __restrict__ edst, int* __restrict__ counts, int E) {
  int i = blockIdx.x * blockDim.x + threadIdx.x;
  if (i < n4) {
    float4 v = X[i];
    ushort4 o;
    o.x = f2bf(v.x); o.y = f2bf(v.y); o.z = f2bf(v.z); o.w = f2bf(v.w);
    Xb[i] = o;
  }
  if (i < 128 * 512) {
    int o = i >> 9, c = i & 511;
    int k = c >> 2, b = c & 3;
    W2T[i] = f2bf(w_bases[(b * D_IN + k) * D_OUT + o]);
  }
  if (i < E) atomicAdd(&counts[edst[i]], 1);
}

// ---------- 2) CSR build ----------
__global__ void k_scan1(const int* __restrict__ counts, int* __restrict__ localsc,
                        int* __restrict__ bsum, int Nn) {
  __shared__ int s[256];
  int i = blockIdx.x * 256 + threadIdx.x;
  int v = (i < Nn) ? counts[i] : 0;
  s[threadIdx.x] = v;
  __syncthreads();
  for (int off = 1; off < 256; off <<= 1) {
    int t = 0;
    if (threadIdx.x >= off) t = s[threadIdx.x - off];
    __syncthreads();
    s[threadIdx.x] += t;
    __syncthreads();
  }
  if (i < Nn) localsc[i] = s[threadIdx.x] - v;
  if (threadIdx.x == 255) bsum[blockIdx.x] = s[255];
}

// fused scan2+scan3: each block redundantly reduces bsum[0..blockIdx.x) (tiny)
__global__ void k_scan23(const int* __restrict__ localsc, const int* __restrict__ bsum,
                         int* __restrict__ offsets, int* __restrict__ cursor, int Nn, int E) {
  __shared__ int red[256];
  int acc = 0;
  for (int j = threadIdx.x; j < blockIdx.x; j += 256) acc += bsum[j];
  red[threadIdx.x] = acc;
  __syncthreads();
  for (int off = 128; off > 0; off >>= 1) {
    if (threadIdx.x < off) red[threadIdx.x] += red[threadIdx.x + off];
    __syncthreads();
  }
  int pref = red[0];
  int i = blockIdx.x * 256 + threadIdx.x;
  if (i < Nn) {
    int v = localsc[i] + pref;
    offsets[i] = v;
    cursor[i] = v;
  }
  if (i == 0) offsets[Nn] = E;
}

// SoA bucket: srcs[] u32 + coef[] float4 (= val * w_rel[rel], fp32 — numeric
// path verified PASS in the R2 bench). Both are WAVE-UNIFORM consumables in
// the agg kernel -> scalar s_load there, zero vmcnt pollution.
__global__ void k_bucket(const int* __restrict__ src, const int* __restrict__ dst,
                         const int* __restrict__ rel, const float* __restrict__ val,
                         const float* __restrict__ w_rel, int* __restrict__ cursor,
                         unsigned* __restrict__ srcs, float4* __restrict__ coef, int E) {
  int i = blockIdx.x * blockDim.x + threadIdx.x;
  if (i >= E) return;
  int d = dst[i];
  int pos = atomicAdd(&cursor[d], 1);
  float v = val[i];
  const float4 w = *(const float4*)(w_rel + rel[i] * 4);
  srcs[pos] = (unsigned)src[i];
  coef[pos] = make_float4(v * w.x, v * w.y, v * w.z, v * w.w);
}

// ---------- 3) fused: per-dst basis aggregation (LDS) + MFMA transform ----------
// Block = 4 waves, 32 dst rows. Wave w owns dsts [w*8, w*8+8) = ONE contiguous
// bucket range, flat edge stream with scalar-branch boundary flushes.
// Phase-1 redesign (R6): edge records are wave-uniform -> scalar s_load into
// SGPRs (lgkmcnt pipe). The vmcnt queue holds ONLY X-row gathers, issued as
// global_load saddr (uniform base + lane*4). 6-slot rotating pipeline,
// 24 edges/iter: src-load +1 sub-block before gather (covers K$ latency),
// gather +3 sub-blocks before consume (~420cy, covers L3 gather latency),
// coef-load +1 sub-block before consume. ACCT = 2 unpack + 8 v_fma (SGPR coef).
__global__ __launch_bounds__(256, 4)
void k_agg_gemm(const unsigned* __restrict__ esrcs, const float4* __restrict__ ecoef,
                const int* __restrict__ offsets, const unsigned* __restrict__ Xb2,
                const unsigned short* __restrict__ W2T, float* __restrict__ out, int Nn) {
  __shared__ __align__(16) unsigned short aggS[32][520];  // pitch 520: 2-way alias (free)

  const int wave = threadIdx.x >> 6, lane = threadIdx.x & 63;
  const int d0 = blockIdx.x * 32 + wave * 8;
  const floatx2 zf2 = {0.f, 0.f};

  // lane l (0..8) loads offsets[d0+l]; readlane -> SGPR bounds
  int oidx = d0 + (lane < 8 ? lane : 8);
  if (oidx > Nn) oidx = Nn;
  const int offv = offsets[oidx];
  const int s0 = __builtin_amdgcn_readlane(offv, 0);
  const int e8 = __builtin_amdgcn_readlane(offv, 8);

  floatx2 a0 = zf2, a1 = zf2, a2 = zf2, a3 = zf2;
  int row = 0;
  int bnd = __builtin_amdgcn_readlane(offv, 1);

#define FLUSH()                                                      \
  do {                                                               \
    uint4 o_;                                                        \
    o_.x = pack2bf(a0.x, a1.x);                                      \
    o_.y = pack2bf(a2.x, a3.x);                                      \
    o_.z = pack2bf(a0.y, a1.y);                                      \
    o_.w = pack2bf(a2.y, a3.y);                                      \
    *(uint4*)&aggS[wave * 8 + row][lane * 8] = o_;                   \
    a0 = zf2; a1 = zf2; a2 = zf2; a3 = zf2;                          \
    ++row;                                                           \
    bnd = (row < 8) ? __builtin_amdgcn_readlane(offv, row + 1)       \
                    : 0x7fffffff;                                    \
  } while (0)

  // SSRC: 4 uniform src ids -> SGPRs (s_load). Clamped to ce (safe over-issue).
#define SSRC(S, BASE)                                                \
  do {                                                               \
    int b_ = (BASE);                                                 \
    int t0_ = b_ < ce ? b_ : ce;                                     \
    int t1_ = b_ + 1 < ce ? b_ + 1 : ce;                             \
    int t2_ = b_ + 2 < ce ? b_ + 2 : ce;                             \
    int t3_ = b_ + 3 < ce ? b_ + 3 : ce;                             \
    s##S##0 = esrcs[t0_]; s##S##1 = esrcs[t1_];                      \
    s##S##2 = esrcs[t2_]; s##S##3 = esrcs[t3_];                      \
  } while (0)

  // GATH: 4 gathers, uniform row base (SGPR) + lane*4 voffset
#define GATH(S)                                                      \
  do {                                                               \
    y##S##0 = Xb2[((size_t)s##S##0 << 6) + lane];                    \
    y##S##1 = Xb2[((size_t)s##S##1 << 6) + lane];                    \
    y##S##2 = Xb2[((size_t)s##S##2 << 6) + lane];                    \
    y##S##3 = Xb2[((size_t)s##S##3 << 6) + lane];                    \
  } while (0)

  // SCOEF: 4 uniform float4 coef loads -> SGPRs (s_load_dwordx4)
#define SCOEF(S, BASE)                                               \
  do {                                                               \
    int b_ = (BASE);                                                 \
    int t0_ = b_ < ce ? b_ : ce;                                     \
    int t1_ = b_ + 1 < ce ? b_ + 1 : ce;                             \
    int t2_ = b_ + 2 < ce ? b_ + 2 : ce;                             \
    int t3_ = b_ + 3 < ce ? b_ + 3 : ce;                             \
    c##S##0 = ecoef[t0_]; c##S##1 = ecoef[t1_];                      \
    c##S##2 = ecoef[t2_]; c##S##3 = ecoef[t3_];                      \
  } while (0)

  // ACCT1: one edge: scalar guard + boundary flush + 2 unpack + 8 fma
#define ACCT1(EI, C, Y)                                              \
  do {                                                               \
    if ((EI) < e8) {                                                 \
      while ((EI) == bnd) FLUSH();                                   \
      floatx2 x_;                                                    \
      x_.x = bflo(Y);                                                \
      x_.y = bfhi(Y);                                                \
      a0 += (C).x * x_;                                              \
      a1 += (C).y * x_;                                              \
      a2 += (C).z * x_;                                              \
      a3 += (C).w * x_;                                              \
    }                                                                \
  } while (0)

#define ACCT4(S, EI0)                                                \
  do {                                                               \
    ACCT1((EI0), c##S##0, y##S##0);                                  \
    ACCT1((EI0) + 1, c##S##1, y##S##1);                              \
    ACCT1((EI0) + 2, c##S##2, y##S##2);                              \
    ACCT1((EI0) + 3, c##S##3, y##S##3);                              \
  } while (0)

  if (s0 < e8) {
    const int ce = e8 - 1;
    unsigned s00, s01, s02, s03, s10, s11, s12, s13, s20, s21, s22, s23;
    unsigned s30, s31, s32, s33, s40, s41, s42, s43, s50, s51, s52, s53;
    unsigned y00, y01, y02, y03, y10, y11, y12, y13, y20, y21, y22, y23;
    unsigned y30, y31, y32, y33, y40, y41, y42, y43, y50, y51, y52, y53;
    float4 c00, c01, c02, c03, c10, c11, c12, c13, c20, c21, c22, c23;
    float4 c30, c31, c32, c33, c40, c41, c42, c43, c50, c51, c52, c53;
    // prologue: establish steady-state invariant for j=0
    SSRC(0, s0); SSRC(1, s0 + 4); SSRC(2, s0 + 8); SSRC(3, s0 + 12);
    GATH(0); GATH(1); GATH(2);
    SCOEF(0, s0);
    int gi = s0;
    while (gi < e8) {
      // j=0
      SSRC(4, gi + 16); GATH(3); SCOEF(1, gi + 4); ACCT4(0, gi);
      // j=1
      SSRC(5, gi + 20); GATH(4); SCOEF(2, gi + 8); ACCT4(1, gi + 4);
      // j=2
      SSRC(0, gi + 24); GATH(5); SCOEF(3, gi + 12); ACCT4(2, gi + 8);
      // j=3
      SSRC(1, gi + 28); GATH(0); SCOEF(4, gi + 16); ACCT4(3, gi + 12);
      // j=4
      SSRC(2, gi + 32); GATH(1); SCOEF(5, gi + 20); ACCT4(4, gi + 16);
      // j=5
      SSRC(3, gi + 36); GATH(2); SCOEF(0, gi + 24); ACCT4(5, gi + 20);
      gi += 24;
    }
  }
  while (row < 8) FLUSH();  // trailing (and fully-empty) rows

  __syncthreads();

  // ---- phase 2: 32x128 output tile via 16x16x32 MFMA, K=512 ----
  const int q = lane >> 4, r16 = lane & 15;
  const int wn = wave * 32;
  const floatx4 zero = {0.f, 0.f, 0.f, 0.f};
  floatx4 acc[2][2];
  acc[0][0] = zero; acc[0][1] = zero; acc[1][0] = zero; acc[1][1] = zero;

#pragma unroll 4
  for (int k0 = 0; k0 < 512; k0 += 32) {
    int ka = k0 + q * 8;
    short8 af[2], bfv[2];
    af[0] = *(const short8*)&aggS[r16][ka];
    af[1] = *(const short8*)&aggS[16 + r16][ka];
    bfv[0] = *(const short8*)(W2T + (size_t)(wn + r16) * 512 + ka);
    bfv[1] = *(const short8*)(W2T + (size_t)(wn + 16 + r16) * 512 + ka);
#pragma unroll
    for (int i = 0; i < 2; ++i)
#pragma unroll
      for (int j = 0; j < 2; ++j)
        acc[i][j] = __builtin_amdgcn_mfma_f32_16x16x32_bf16(af[i], bfv[j], acc[i][j], 0, 0, 0);
  }

  // epilogue: C/D layout col=lane&15, row=(lane>>4)*4+p  [m89/m91-verified]
#pragma unroll
  for (int i = 0; i < 2; ++i) {
#pragma unroll
    for (int j = 0; j < 2; ++j) {
#pragma unroll
      for (int p = 0; p < 4; ++p) {
        int prow = i * 16 + q * 4 + p;
        int col = wn + j * 16 + r16;
        int grow = blockIdx.x * 32 + prow;
        if (grow < Nn) out[(size_t)grow * 128 + col] = acc[i][j][p];
      }
    }
  }
}

extern "C" void kernel_launch(void* const* d_in, const int* in_sizes, int n_in,
                              void* d_out, int out_size, void* d_ws, size_t ws_size,
                              hipStream_t stream) {
  const float* X = (const float*)d_in[0];
  const int* esrc = (const int*)d_in[1];
  const int* edst = (const int*)d_in[2];
  const int* erel = (const int*)d_in[3];
  const float* eval_ = (const float*)d_in[4];
  const float* w_bases = (const float*)d_in[5];
  const float* w_rel = (const float*)d_in[6];
  const int Nn = in_sizes[0] / D_IN;  // 100000
  const int E = in_sizes[1];          // 640000

  char* ws = (char*)d_ws;
  size_t off = 0;
  auto alloc = [&](size_t bytes) -> char* {
    char* p = ws + off;
    off += (bytes + 255) & ~(size_t)255;
    return p;
  };
  unsigned short* Xb = (unsigned short*)alloc((size_t)Nn * D_IN * 2);     // 25.6 MB
  unsigned short* W2T = (unsigned short*)alloc((size_t)128 * 512 * 2);    // 128 KB
  int* counts = (int*)alloc((size_t)Nn * 4);
  int* cursor = (int*)alloc((size_t)Nn * 4);
  int* offsets = (int*)alloc((size_t)(Nn + 1) * 4);
  int* localsc = (int*)alloc((size_t)Nn * 4);
  int* bsum = (int*)alloc(4096);
  unsigned* srcs = (unsigned*)alloc((size_t)E * 4);                       // 2.56 MB
  float4* coef = (float4*)alloc((size_t)E * 16);                          // 10.24 MB
  (void)ws_size;

  int n4 = Nn * D_IN / 4;  // 3.2M
  hipMemsetAsync(counts, 0, (size_t)Nn * 4, stream);
  k_prep<<<(n4 + 255) / 256, 256, 0, stream>>>((const float4*)X, (ushort4*)Xb, n4,
                                               w_bases, W2T, edst, counts, E);

  int nb = (Nn + 255) / 256;
  k_scan1<<<nb, 256, 0, stream>>>(counts, localsc, bsum, Nn);
  k_scan23<<<nb, 256, 0, stream>>>(localsc, bsum, offsets, cursor, Nn, E);
  k_bucket<<<(E + 255) / 256, 256, 0, stream>>>(esrc, edst, erel, eval_, w_rel,
                                                cursor, srcs, coef, E);

  // fused aggregation + transform: 4-wave blocks, 32 dsts each
  k_agg_gemm<<<(Nn + 31) / 32, 256, 0, stream>>>(srcs, coef, offsets,
                                                 (const unsigned*)Xb, W2T,
                                                 (float*)d_out, Nn);
}